// Round 3
// baseline (865.316 us; speedup 1.0000x reference)
//
#include <hip/hip_runtime.h>

// NLSearch: B=1, T=4, C=64 (2 heads x 32ch), H=W=192, stride0=4 -> 48x48 queries,
// patch 7x7, offsets dt{-1,0,1} x di,dj{-3..4} (L=192), top-K=7.
// Block = (head, t, qi, qj-pair): 9216 blocks, 256 threads.
// Out: vals f32 [2][9216][7] (129024) then inds [2][9216][7][3] (387072).

#define HH 192
#define WW 192
#define HW (HH * WW)

// LDS: Bs [c][u 0..13][v 0..19], c-stride 292 (292/4=73 odd, ==1 mod 8 -> uniform quads)
//      As overlaid [c][y 0..6][v 0..11], c-stride 84 (consumed to regs before B staged)
//      score [2][192]
#define BS_CSTR 292
#define BS_SZ   (32 * BS_CSTR)   // 9344 floats
#define AS_CSTR 84

__device__ __forceinline__ int reflect_i(int idx, int n) {
    idx = idx < 0 ? -idx : idx;
    idx = idx >= n ? 2 * (n - 1) - idx : idx;
    return idx;
}

template <int CTRL>
__device__ __forceinline__ float dpp_add(float x) {
    int y = __builtin_amdgcn_update_dpp(0, __float_as_int(x), CTRL, 0xf, 0xf, true);
    return x + __int_as_float(y);
}

// lane31 <- sum(lanes 0..31), lane63 <- sum(lanes 32..63); VALU pipe, no LDS.
__device__ __forceinline__ float reduce32(float v) {
    v = dpp_add<0x111>(v);  // row_shr:1
    v = dpp_add<0x112>(v);  // row_shr:2
    v = dpp_add<0x114>(v);  // row_shr:4
    v = dpp_add<0x118>(v);  // row_shr:8
    v = dpp_add<0x142>(v);  // row_bcast15
    return v;
}

__global__ __launch_bounds__(256, 4) void nls_kernel(
    const float* __restrict__ vid0,
    const float* __restrict__ vid1,
    float* __restrict__ out)
{
    __shared__ float smem[BS_SZ + 2 * 192];
    float* Bs = smem;
    float* As = smem;             // overlaid
    float* score = smem + BS_SZ;

    // XCD swizzle: xcd = blk&7 -> qi band; inner (hd, t, qi_l, qjp)
    const int b    = blockIdx.x;
    const int xcd  = b & 7;
    const int loc  = b >> 3;
    const int qjp  = loc % 24;
    const int r1   = loc / 24;
    const int qi_l = r1 % 6;
    const int r2   = r1 / 6;
    const int t    = r2 & 3;
    const int hd   = r2 >> 2;
    const int qi   = xcd * 6 + qi_l;

    const int qh  = qi * 4;
    const int qw0 = qjp * 8;

    const int tid  = threadIdx.x;
    const int lane = tid & 63;
    const int wid  = tid >> 6;

    const bool intA = (qi >= 1) && (qjp >= 1) && (qjp <= 22);
    const bool intB = (qi >= 2) && (qi <= 46) && (qjp >= 1) && (qjp <= 22);

    // ---- stage A region [32c][7u][12v] ----
    if (intA) {
        const int sc = tid & 31;
        const int gg = tid >> 5;
        const float* src = vid0 + (size_t)(t * 64 + hd * 32 + sc) * HW
                         + (qh - 3) * WW + (qw0 - 3);
        float* dstc = As + sc * AS_CSTR;
        for (int it = gg; it < 21; it += 8) {
            int u = it / 3, grp = it - u * 3;
            float4 val = *(const float4*)(src + u * WW + 4 * grp);
            *(float4*)(dstc + u * 12 + 4 * grp) = val;
        }
    } else {
        const int sc = tid >> 3;
        const int vl = tid & 7;
        const float* src = vid0 + (size_t)(t * 64 + hd * 32 + sc) * HW;
        const int wa0 = reflect_i(qw0 - 3 + vl, WW);
        const int wa1 = (vl < 4) ? reflect_i(qw0 + 5 + vl, WW) : 0;
        float* dst = As + sc * AS_CSTR + vl;
        #pragma unroll
        for (int u = 0; u < 7; ++u) {
            int hh = reflect_i(qh - 3 + u, HH);
            const float* rp = src + hh * WW;
            dst[u * 12] = rp[wa0];
            if (vl < 4) dst[u * 12 + 8] = rp[wa1];
        }
    }
    __syncthreads();

    // ---- A -> registers. lane = (c, hhalf); wave = (q, d) ----
    const int c     = lane & 31;
    const int hhalf = lane >> 5;   // dj half
    const int q     = wid >> 1;    // query in pair
    const int d     = wid & 1;     // di half

    float a[7][8];
    {
        const float* Ab = As + c * AS_CSTR + 4 * q;
        #pragma unroll
        for (int y = 0; y < 7; ++y) {
            *(float4*)&a[y][0] = *(const float4*)(Ab + y * 12);
            *(float4*)&a[y][4] = *(const float4*)(Ab + y * 12 + 4);
        }
    }

    const float* Bc = Bs + c * BS_CSTR + (4 * d) * 20 + 4 * q + 4 * hhalf;

    int tprev = -1;
    for (int dtI = 0; dtI < 3; ++dtI) {
        int tp = t + dtI - 1;
        tp = tp < 0 ? 0 : (tp > 3 ? 3 : tp);

        __syncthreads();  // a-regs loaded / prev compute done / prev scores visible

        if (tp == tprev) {
            // clamp duplicate: bitwise copy -> exact ties, lower l wins
            if (tid < 128) {
                int qq = tid >> 6, o = tid & 63;
                score[qq * 192 + dtI * 64 + o] = score[qq * 192 + (dtI - 1) * 64 + o];
            }
            continue;
        }
        tprev = tp;

        // ---- stage B [32c][14u][20v] ----
        if (intB) {
            const int sc = tid & 31;
            const int gg = tid >> 5;
            const float* src = vid1 + (size_t)(tp * 64 + hd * 32 + sc) * HW
                             + (qh - 6) * WW + (qw0 - 6);
            float* dstc = Bs + sc * BS_CSTR;
            for (int it = gg; it < 70; it += 8) {
                int u = it / 5, grp = it - u * 5;
                float4 val = *(const float4*)(src + u * WW + 4 * grp);
                *(float4*)(dstc + u * 20 + 4 * grp) = val;
            }
        } else {
            const int sc = tid >> 3;
            const int vl = tid & 7;
            const float* src = vid1 + (size_t)(tp * 64 + hd * 32 + sc) * HW;
            const int w0 = reflect_i(qw0 - 6 + vl, WW);
            const int w1 = reflect_i(qw0 + 2 + vl, WW);
            const int w2 = (vl < 4) ? reflect_i(qw0 + 10 + vl, WW) : 0;
            float* dst = Bs + sc * BS_CSTR + vl;
            #pragma unroll
            for (int u = 0; u < 14; ++u) {
                int hh2 = reflect_i(qh - 6 + u, HH);
                const float* rp = src + hh2 * WW;
                dst[u * 20]     = rp[w0];
                dst[u * 20 + 8] = rp[w1];
                if (vl < 4) dst[u * 20 + 16] = rp[w2];
            }
        }
        __syncthreads();

        // ---- compute: r-loop, each B row read once (3 b128), consumed immediately ----
        {
            float acc[16];
            #pragma unroll
            for (int k = 0; k < 16; ++k) acc[k] = 0.f;

            #pragma unroll
            for (int r = 0; r < 10; ++r) {
                float rw[12];
                *(float4*)&rw[0] = *(const float4*)(Bc + r * 20);
                *(float4*)&rw[4] = *(const float4*)(Bc + r * 20 + 4);
                *(float4*)&rw[8] = *(const float4*)(Bc + r * 20 + 8);
                const int dlo = r > 6 ? r - 6 : 0;
                const int dhi = r < 3 ? r : 3;
                #pragma unroll
                for (int dip = 0; dip < 4; ++dip) {
                    if (dip >= dlo && dip <= dhi) {
                        const int y = r - dip;
                        #pragma unroll
                        for (int djp = 0; djp < 4; ++djp) {
                            #pragma unroll
                            for (int x = 0; x < 7; ++x) {
                                acc[dip * 4 + djp] =
                                    fmaf(a[y][x], rw[djp + x], acc[dip * 4 + djp]);
                            }
                        }
                    }
                }
            }

            #pragma unroll
            for (int k = 0; k < 16; ++k) acc[k] = reduce32(acc[k]);

            if ((lane & 31) == 31) {
                float* sp = &score[q * 192 + dtI * 64 + 4 * hhalf];
                #pragma unroll
                for (int dip = 0; dip < 4; ++dip) {
                    float4 v4 = make_float4(acc[dip * 4 + 0], acc[dip * 4 + 1],
                                            acc[dip * 4 + 2], acc[dip * 4 + 3]);
                    *(float4*)(sp + (4 * d + dip) * 8) = v4;
                }
            }
        }
    }

    __syncthreads();

    // ---- top-K=7 over 192 per query; waves 0,1 ----
    if (wid < 2) {
        const int qq = wid;
        const int qj = 2 * qjp + qq;
        float v0 = score[qq * 192 + lane];
        float v1 = score[qq * 192 + 64 + lane];
        float v2 = score[qq * 192 + 128 + lane];
        const int qglob = (t * 48 + qi) * 48 + qj;
        const int vbase = (hd * 9216 + qglob) * 7;
        const int ibase = 129024 + vbase * 3;
        for (int r = 0; r < 7; ++r) {
            float bv = v0; int bi = lane;
            if (v1 > bv) { bv = v1; bi = lane + 64; }
            if (v2 > bv) { bv = v2; bi = lane + 128; }
            #pragma unroll
            for (int m = 1; m <= 32; m <<= 1) {
                float ov = __shfl_xor(bv, m);
                int   oi = __shfl_xor(bi, m);
                if (ov > bv || (ov == bv && oi < bi)) { bv = ov; bi = oi; }
            }
            if (lane == 0) {
                out[vbase + r] = bv;
                int dtSel = bi >> 6;
                int rr    = bi & 63;
                int diSel = (rr >> 3) - 3;
                int djSel = (rr & 7) - 3;
                int ts = t + dtSel - 1;
                ts = ts < 0 ? 0 : (ts > 3 ? 3 : ts);
                int hs = reflect_i(qh + diSel, HH);
                int ws = reflect_i(qj * 4 + djSel, WW);
                float* op = out + ibase + 3 * r;
                op[0] = (float)ts;
                op[1] = (float)hs;
                op[2] = (float)ws;
            }
            if ((bi & 63) == lane) {
                int slot = bi >> 6;
                if (slot == 0)      v0 = -3.4e38f;
                else if (slot == 1) v1 = -3.4e38f;
                else                v2 = -3.4e38f;
            }
        }
    }
}

extern "C" void kernel_launch(void* const* d_in, const int* in_sizes, int n_in,
                              void* d_out, int out_size, void* d_ws, size_t ws_size,
                              hipStream_t stream) {
    const float* vid0 = (const float*)d_in[0];
    const float* vid1 = (const float*)d_in[1];
    float* out = (float*)d_out;
    dim3 grid(9216);
    dim3 block(256);
    hipLaunchKernelGGL(nls_kernel, grid, block, 0, stream, vid0, vid1, out);
}

// Round 4
// 430.603 us; speedup vs baseline: 2.0095x; 2.0095x over previous
//
#include <hip/hip_runtime.h>

// NLSearch: B=1, T=4, C=64 (2 heads x 32ch), H=W=192, stride0=4 -> 48x48 queries,
// patch 7x7, offsets dt{-1,0,1} x di,dj{-3..4} (L=192), top-K=7.
// Block = (head, t, qi, qj-pair): 9216 blocks, 256 threads.
// Out: vals f32 [2][9216][7] (129024) then inds [2][9216][7][3] (387072).
//
// NOTE: do NOT set a min-waves arg in __launch_bounds__ — 256,3 capped VGPR=84,
// 256,4 capped VGPR=64; both spilled the a[]/rw[]/acc[] arrays to scratch
// (R3: 3.1 GB HBM scratch traffic, 865us). Plain (256) -> 128 VGPR, no spill.

#define HH 192
#define WW 192
#define HW (HH * WW)

// LDS: Bs [c][u 0..13][v 0..19], c-stride 292
//      As overlaid [c][y 0..6][v 0..11], c-stride 84 (consumed to regs before B staged)
//      score [2][192]
#define BS_CSTR 292
#define BS_SZ   (32 * BS_CSTR)   // 9344 floats
#define AS_CSTR 84

__device__ __forceinline__ int reflect_i(int idx, int n) {
    idx = idx < 0 ? -idx : idx;
    idx = idx >= n ? 2 * (n - 1) - idx : idx;
    return idx;
}

template <int CTRL>
__device__ __forceinline__ float dpp_add(float x) {
    int y = __builtin_amdgcn_update_dpp(0, __float_as_int(x), CTRL, 0xf, 0xf, true);
    return x + __int_as_float(y);
}

// lane31 <- sum(lanes 0..31), lane63 <- sum(lanes 32..63); VALU pipe, no LDS.
__device__ __forceinline__ float reduce32(float v) {
    v = dpp_add<0x111>(v);  // row_shr:1
    v = dpp_add<0x112>(v);  // row_shr:2
    v = dpp_add<0x114>(v);  // row_shr:4
    v = dpp_add<0x118>(v);  // row_shr:8
    v = dpp_add<0x142>(v);  // row_bcast15
    return v;
}

__global__ __launch_bounds__(256) void nls_kernel(
    const float* __restrict__ vid0,
    const float* __restrict__ vid1,
    float* __restrict__ out)
{
    __shared__ float smem[BS_SZ + 2 * 192];
    float* Bs = smem;
    float* As = smem;             // overlaid
    float* score = smem + BS_SZ;

    // XCD swizzle: xcd = blk&7 -> qi band; inner (hd, t, qi_l, qjp)
    const int b    = blockIdx.x;
    const int xcd  = b & 7;
    const int loc  = b >> 3;
    const int qjp  = loc % 24;
    const int r1   = loc / 24;
    const int qi_l = r1 % 6;
    const int r2   = r1 / 6;
    const int t    = r2 & 3;
    const int hd   = r2 >> 2;
    const int qi   = xcd * 6 + qi_l;

    const int qh  = qi * 4;
    const int qw0 = qjp * 8;

    const int tid  = threadIdx.x;
    const int lane = tid & 63;
    const int wid  = tid >> 6;

    const bool intA = (qi >= 1) && (qjp >= 1) && (qjp <= 22);
    const bool intB = (qi >= 2) && (qi <= 46) && (qjp >= 1) && (qjp <= 22);

    // ---- stage A region [32c][7u][12v] ----
    if (intA) {
        const int sc = tid & 31;
        const int gg = tid >> 5;
        const float* src = vid0 + (size_t)(t * 64 + hd * 32 + sc) * HW
                         + (qh - 3) * WW + (qw0 - 3);
        float* dstc = As + sc * AS_CSTR;
        for (int it = gg; it < 21; it += 8) {
            int u = it / 3, grp = it - u * 3;
            float4 val = *(const float4*)(src + u * WW + 4 * grp);
            *(float4*)(dstc + u * 12 + 4 * grp) = val;
        }
    } else {
        const int sc = tid >> 3;
        const int vl = tid & 7;
        const float* src = vid0 + (size_t)(t * 64 + hd * 32 + sc) * HW;
        const int wa0 = reflect_i(qw0 - 3 + vl, WW);
        const int wa1 = (vl < 4) ? reflect_i(qw0 + 5 + vl, WW) : 0;
        float* dst = As + sc * AS_CSTR + vl;
        #pragma unroll
        for (int u = 0; u < 7; ++u) {
            int hh = reflect_i(qh - 3 + u, HH);
            const float* rp = src + hh * WW;
            dst[u * 12] = rp[wa0];
            if (vl < 4) dst[u * 12 + 8] = rp[wa1];
        }
    }
    __syncthreads();

    // ---- A -> registers. lane = (c, hhalf); wave = (q, d) ----
    const int c     = lane & 31;
    const int hhalf = lane >> 5;   // dj half
    const int q     = wid >> 1;    // query in pair
    const int d     = wid & 1;     // di half

    float a[7][8];
    {
        const float* Ab = As + c * AS_CSTR + 4 * q;
        #pragma unroll
        for (int y = 0; y < 7; ++y) {
            *(float4*)&a[y][0] = *(const float4*)(Ab + y * 12);
            *(float4*)&a[y][4] = *(const float4*)(Ab + y * 12 + 4);
        }
    }

    const float* Bc = Bs + c * BS_CSTR + (4 * d) * 20 + 4 * q + 4 * hhalf;

    int tprev = -1;
    for (int dtI = 0; dtI < 3; ++dtI) {
        int tp = t + dtI - 1;
        tp = tp < 0 ? 0 : (tp > 3 ? 3 : tp);

        __syncthreads();  // a-regs loaded / prev compute done / prev scores visible

        if (tp == tprev) {
            // clamp duplicate: bitwise copy -> exact ties, lower l wins
            if (tid < 128) {
                int qq = tid >> 6, o = tid & 63;
                score[qq * 192 + dtI * 64 + o] = score[qq * 192 + (dtI - 1) * 64 + o];
            }
            continue;
        }
        tprev = tp;

        // ---- stage B [32c][14u][20v] ----
        if (intB) {
            const int sc = tid & 31;
            const int gg = tid >> 5;
            const float* src = vid1 + (size_t)(tp * 64 + hd * 32 + sc) * HW
                             + (qh - 6) * WW + (qw0 - 6);
            float* dstc = Bs + sc * BS_CSTR;
            for (int it = gg; it < 70; it += 8) {
                int u = it / 5, grp = it - u * 5;
                float4 val = *(const float4*)(src + u * WW + 4 * grp);
                *(float4*)(dstc + u * 20 + 4 * grp) = val;
            }
        } else {
            const int sc = tid >> 3;
            const int vl = tid & 7;
            const float* src = vid1 + (size_t)(tp * 64 + hd * 32 + sc) * HW;
            const int w0 = reflect_i(qw0 - 6 + vl, WW);
            const int w1 = reflect_i(qw0 + 2 + vl, WW);
            const int w2 = (vl < 4) ? reflect_i(qw0 + 10 + vl, WW) : 0;
            float* dst = Bs + sc * BS_CSTR + vl;
            #pragma unroll
            for (int u = 0; u < 14; ++u) {
                int hh2 = reflect_i(qh - 6 + u, HH);
                const float* rp = src + hh2 * WW;
                dst[u * 20]     = rp[w0];
                dst[u * 20 + 8] = rp[w1];
                if (vl < 4) dst[u * 20 + 16] = rp[w2];
            }
        }
        __syncthreads();

        // ---- compute: r-loop, each B row read once (3 b128), consumed immediately ----
        {
            float acc[16];
            #pragma unroll
            for (int k = 0; k < 16; ++k) acc[k] = 0.f;

            #pragma unroll
            for (int r = 0; r < 10; ++r) {
                float rw[12];
                *(float4*)&rw[0] = *(const float4*)(Bc + r * 20);
                *(float4*)&rw[4] = *(const float4*)(Bc + r * 20 + 4);
                *(float4*)&rw[8] = *(const float4*)(Bc + r * 20 + 8);
                const int dlo = r > 6 ? r - 6 : 0;
                const int dhi = r < 3 ? r : 3;
                #pragma unroll
                for (int dip = 0; dip < 4; ++dip) {
                    if (dip >= dlo && dip <= dhi) {
                        const int y = r - dip;
                        #pragma unroll
                        for (int djp = 0; djp < 4; ++djp) {
                            #pragma unroll
                            for (int x = 0; x < 7; ++x) {
                                acc[dip * 4 + djp] =
                                    fmaf(a[y][x], rw[djp + x], acc[dip * 4 + djp]);
                            }
                        }
                    }
                }
            }

            #pragma unroll
            for (int k = 0; k < 16; ++k) acc[k] = reduce32(acc[k]);

            if ((lane & 31) == 31) {
                float* sp = &score[q * 192 + dtI * 64 + 4 * hhalf];
                #pragma unroll
                for (int dip = 0; dip < 4; ++dip) {
                    float4 v4 = make_float4(acc[dip * 4 + 0], acc[dip * 4 + 1],
                                            acc[dip * 4 + 2], acc[dip * 4 + 3]);
                    *(float4*)(sp + (4 * d + dip) * 8) = v4;
                }
            }
        }
    }

    __syncthreads();

    // ---- top-K=7 over 192 per query; waves 0,1 ----
    if (wid < 2) {
        const int qq = wid;
        const int qj = 2 * qjp + qq;
        float v0 = score[qq * 192 + lane];
        float v1 = score[qq * 192 + 64 + lane];
        float v2 = score[qq * 192 + 128 + lane];
        const int qglob = (t * 48 + qi) * 48 + qj;
        const int vbase = (hd * 9216 + qglob) * 7;
        const int ibase = 129024 + vbase * 3;
        for (int r = 0; r < 7; ++r) {
            float bv = v0; int bi = lane;
            if (v1 > bv) { bv = v1; bi = lane + 64; }
            if (v2 > bv) { bv = v2; bi = lane + 128; }
            #pragma unroll
            for (int m = 1; m <= 32; m <<= 1) {
                float ov = __shfl_xor(bv, m);
                int   oi = __shfl_xor(bi, m);
                if (ov > bv || (ov == bv && oi < bi)) { bv = ov; bi = oi; }
            }
            if (lane == 0) {
                out[vbase + r] = bv;
                int dtSel = bi >> 6;
                int rr    = bi & 63;
                int diSel = (rr >> 3) - 3;
                int djSel = (rr & 7) - 3;
                int ts = t + dtSel - 1;
                ts = ts < 0 ? 0 : (ts > 3 ? 3 : ts);
                int hs = reflect_i(qh + diSel, HH);
                int ws = reflect_i(qj * 4 + djSel, WW);
                float* op = out + ibase + 3 * r;
                op[0] = (float)ts;
                op[1] = (float)hs;
                op[2] = (float)ws;
            }
            if ((bi & 63) == lane) {
                int slot = bi >> 6;
                if (slot == 0)      v0 = -3.4e38f;
                else if (slot == 1) v1 = -3.4e38f;
                else                v2 = -3.4e38f;
            }
        }
    }
}

extern "C" void kernel_launch(void* const* d_in, const int* in_sizes, int n_in,
                              void* d_out, int out_size, void* d_ws, size_t ws_size,
                              hipStream_t stream) {
    const float* vid0 = (const float*)d_in[0];
    const float* vid1 = (const float*)d_in[1];
    float* out = (float*)d_out;
    dim3 grid(9216);
    dim3 block(256);
    hipLaunchKernelGGL(nls_kernel, grid, block, 0, stream, vid0, vid1, out);
}

// Round 5
// 331.485 us; speedup vs baseline: 2.6104x; 1.2990x over previous
//
#include <hip/hip_runtime.h>

// NLSearch: B=1, T=4, C=64 (2 heads x 32ch), H=W=192, stride0=4 -> 48x48 queries,
// patch 7x7, offsets dt{-1,0,1} x di,dj{-3..4} (L=192), top-K=7.
// Block = (head, t, qi, qj-pair): 9216 blocks, 256 threads.
// Out: vals f32 [2][9216][7] (129024) then inds [2][9216][7][3] (387072).
//
// NOTE: do NOT set a min-waves arg in __launch_bounds__ — 256,3 capped VGPR=84,
// 256,4 capped VGPR=64; both spilled a[]/rw[]/acc[] to scratch (R3: 3.1 GB HBM
// scratch traffic). Plain (256) -> ~92 VGPR, no spill.
//
// LDS banking: all B/A accesses are b64-granular with c-stride == 2 (mod 4)
// words: B 282 (26 mod 32 -> 16 distinct even start banks, 2-way = free),
// A 86 (22 mod 32). R4's b128 @ stride 292 (4 mod 32) gave 3.6e7 conflicts.

#define HH 192
#define WW 192
#define HW (HH * WW)

#define BS_CSTR 282              // 14 rows * 20 + 2 pad
#define BS_SZ   (32 * BS_CSTR)   // 9024 floats
#define AS_CSTR 86               // 7 rows * 12 + 2 pad

__device__ __forceinline__ int reflect_i(int idx, int n) {
    idx = idx < 0 ? -idx : idx;
    idx = idx >= n ? 2 * (n - 1) - idx : idx;
    return idx;
}

template <int CTRL>
__device__ __forceinline__ float dpp_add(float x) {
    int y = __builtin_amdgcn_update_dpp(0, __float_as_int(x), CTRL, 0xf, 0xf, true);
    return x + __int_as_float(y);
}

// lane31 <- sum(lanes 0..31), lane63 <- sum(lanes 32..63); VALU pipe, no LDS.
__device__ __forceinline__ float reduce32(float v) {
    v = dpp_add<0x111>(v);  // row_shr:1
    v = dpp_add<0x112>(v);  // row_shr:2
    v = dpp_add<0x114>(v);  // row_shr:4
    v = dpp_add<0x118>(v);  // row_shr:8
    v = dpp_add<0x142>(v);  // row_bcast15
    return v;
}

__global__ __launch_bounds__(256) void nls_kernel(
    const float* __restrict__ vid0,
    const float* __restrict__ vid1,
    float* __restrict__ out)
{
    __shared__ float smem[BS_SZ + 2 * 192];
    float* Bs = smem;
    float* As = smem;             // overlaid; A consumed to regs before B staged
    float* score = smem + BS_SZ;

    // XCD swizzle: xcd = blk&7 -> qi band; inner (hd, t, qi_l, qjp)
    const int b    = blockIdx.x;
    const int xcd  = b & 7;
    const int loc  = b >> 3;
    const int qjp  = loc % 24;
    const int r1   = loc / 24;
    const int qi_l = r1 % 6;
    const int r2   = r1 / 6;
    const int t    = r2 & 3;
    const int hd   = r2 >> 2;
    const int qi   = xcd * 6 + qi_l;

    const int qh  = qi * 4;
    const int qw0 = qjp * 8;

    const int tid  = threadIdx.x;
    const int lane = tid & 63;
    const int wid  = tid >> 6;

    const bool intA = (qi >= 1) && (qjp >= 1) && (qjp <= 22);
    const bool intB = (qi >= 2) && (qi <= 46) && (qjp >= 1) && (qjp <= 22);

    // ---- stage A region [32c][7u][12v] ----
    if (intA) {
        const int sc = tid & 31;
        const int gg = tid >> 5;
        const float* src = vid0 + (size_t)(t * 64 + hd * 32 + sc) * HW
                         + (qh - 3) * WW + (qw0 - 3);
        float* dstc = As + sc * AS_CSTR;
        for (int it = gg; it < 21; it += 8) {
            int u = it / 3, grp = it - u * 3;
            float4 val = *(const float4*)(src + u * WW + 4 * grp);
            float* dp = dstc + u * 12 + 4 * grp;
            *(float2*)(dp)     = make_float2(val.x, val.y);
            *(float2*)(dp + 2) = make_float2(val.z, val.w);
        }
    } else {
        const int sc = tid >> 3;
        const int vl = tid & 7;
        const float* src = vid0 + (size_t)(t * 64 + hd * 32 + sc) * HW;
        const int wa0 = reflect_i(qw0 - 3 + vl, WW);
        const int wa1 = (vl < 4) ? reflect_i(qw0 + 5 + vl, WW) : 0;
        float* dst = As + sc * AS_CSTR + vl;
        #pragma unroll
        for (int u = 0; u < 7; ++u) {
            int hh = reflect_i(qh - 3 + u, HH);
            const float* rp = src + hh * WW;
            dst[u * 12] = rp[wa0];
            if (vl < 4) dst[u * 12 + 8] = rp[wa1];
        }
    }
    __syncthreads();

    // ---- A -> registers. lane = (c, hhalf); wave = (q, d) ----
    const int c     = lane & 31;
    const int hhalf = lane >> 5;   // dj half
    const int q     = wid >> 1;    // query in pair
    const int d     = wid & 1;     // di half

    float a[7][8];
    {
        const float* Ab = As + c * AS_CSTR + 4 * q;
        #pragma unroll
        for (int y = 0; y < 7; ++y) {
            #pragma unroll
            for (int j = 0; j < 4; ++j)
                *(float2*)&a[y][2 * j] = *(const float2*)(Ab + y * 12 + 2 * j);
        }
    }

    const float* Bc = Bs + c * BS_CSTR + (4 * d) * 20 + 4 * q + 4 * hhalf;

    int tprev = -1;
    for (int dtI = 0; dtI < 3; ++dtI) {
        int tp = t + dtI - 1;
        tp = tp < 0 ? 0 : (tp > 3 ? 3 : tp);

        __syncthreads();  // a-regs loaded / prev compute done / prev scores visible

        if (tp == tprev) {
            // clamp duplicate: bitwise copy -> exact ties, lower l wins
            if (tid < 128) {
                int qq = tid >> 6, o = tid & 63;
                score[qq * 192 + dtI * 64 + o] = score[qq * 192 + (dtI - 1) * 64 + o];
            }
            continue;
        }
        tprev = tp;

        // ---- stage B [32c][14u][20v] ----
        if (intB) {
            const int sc = tid & 31;
            const int gg = tid >> 5;
            const float* src = vid1 + (size_t)(tp * 64 + hd * 32 + sc) * HW
                             + (qh - 6) * WW + (qw0 - 6);
            float* dstc = Bs + sc * BS_CSTR;
            for (int it = gg; it < 70; it += 8) {
                int u = it / 5, grp = it - u * 5;
                float4 val = *(const float4*)(src + u * WW + 4 * grp);
                float* dp = dstc + u * 20 + 4 * grp;
                *(float2*)(dp)     = make_float2(val.x, val.y);
                *(float2*)(dp + 2) = make_float2(val.z, val.w);
            }
        } else {
            const int sc = tid >> 3;
            const int vl = tid & 7;
            const float* src = vid1 + (size_t)(tp * 64 + hd * 32 + sc) * HW;
            const int w0 = reflect_i(qw0 - 6 + vl, WW);
            const int w1 = reflect_i(qw0 + 2 + vl, WW);
            const int w2 = (vl < 4) ? reflect_i(qw0 + 10 + vl, WW) : 0;
            float* dst = Bs + sc * BS_CSTR + vl;
            #pragma unroll
            for (int u = 0; u < 14; ++u) {
                int hh2 = reflect_i(qh - 6 + u, HH);
                const float* rp = src + hh2 * WW;
                dst[u * 20]     = rp[w0];
                dst[u * 20 + 8] = rp[w1];
                if (vl < 4) dst[u * 20 + 16] = rp[w2];
            }
        }
        __syncthreads();

        // ---- compute: r-loop, each B row read once (6 b64), consumed immediately ----
        {
            float acc[16];
            #pragma unroll
            for (int k = 0; k < 16; ++k) acc[k] = 0.f;

            #pragma unroll
            for (int r = 0; r < 10; ++r) {
                float rw[12];
                const float* Br = Bc + r * 20;
                #pragma unroll
                for (int j = 0; j < 6; ++j)
                    *(float2*)&rw[2 * j] = *(const float2*)(Br + 2 * j);
                const int dlo = r > 6 ? r - 6 : 0;
                const int dhi = r < 3 ? r : 3;
                #pragma unroll
                for (int dip = 0; dip < 4; ++dip) {
                    if (dip >= dlo && dip <= dhi) {
                        const int y = r - dip;
                        #pragma unroll
                        for (int djp = 0; djp < 4; ++djp) {
                            #pragma unroll
                            for (int x = 0; x < 7; ++x) {
                                acc[dip * 4 + djp] =
                                    fmaf(a[y][x], rw[djp + x], acc[dip * 4 + djp]);
                            }
                        }
                    }
                }
            }

            #pragma unroll
            for (int k = 0; k < 16; ++k) acc[k] = reduce32(acc[k]);

            if ((lane & 31) == 31) {
                float* sp = &score[q * 192 + dtI * 64 + 4 * hhalf];
                #pragma unroll
                for (int dip = 0; dip < 4; ++dip) {
                    float* dp = sp + (4 * d + dip) * 8;
                    *(float2*)(dp)     = make_float2(acc[dip * 4 + 0], acc[dip * 4 + 1]);
                    *(float2*)(dp + 2) = make_float2(acc[dip * 4 + 2], acc[dip * 4 + 3]);
                }
            }
        }
    }

    __syncthreads();

    // ---- top-K=7 over 192 per query; waves 0,1 ----
    if (wid < 2) {
        const int qq = wid;
        const int qj = 2 * qjp + qq;
        float v0 = score[qq * 192 + lane];
        float v1 = score[qq * 192 + 64 + lane];
        float v2 = score[qq * 192 + 128 + lane];
        const int qglob = (t * 48 + qi) * 48 + qj;
        const int vbase = (hd * 9216 + qglob) * 7;
        const int ibase = 129024 + vbase * 3;
        for (int r = 0; r < 7; ++r) {
            float bv = v0; int bi = lane;
            if (v1 > bv) { bv = v1; bi = lane + 64; }
            if (v2 > bv) { bv = v2; bi = lane + 128; }
            #pragma unroll
            for (int m = 1; m <= 32; m <<= 1) {
                float ov = __shfl_xor(bv, m);
                int   oi = __shfl_xor(bi, m);
                if (ov > bv || (ov == bv && oi < bi)) { bv = ov; bi = oi; }
            }
            if (lane == 0) {
                out[vbase + r] = bv;
                int dtSel = bi >> 6;
                int rr    = bi & 63;
                int diSel = (rr >> 3) - 3;
                int djSel = (rr & 7) - 3;
                int ts = t + dtSel - 1;
                ts = ts < 0 ? 0 : (ts > 3 ? 3 : ts);
                int hs = reflect_i(qh + diSel, HH);
                int ws = reflect_i(qj * 4 + djSel, WW);
                float* op = out + ibase + 3 * r;
                op[0] = (float)ts;
                op[1] = (float)hs;
                op[2] = (float)ws;
            }
            if ((bi & 63) == lane) {
                int slot = bi >> 6;
                if (slot == 0)      v0 = -3.4e38f;
                else if (slot == 1) v1 = -3.4e38f;
                else                v2 = -3.4e38f;
            }
        }
    }
}

extern "C" void kernel_launch(void* const* d_in, const int* in_sizes, int n_in,
                              void* d_out, int out_size, void* d_ws, size_t ws_size,
                              hipStream_t stream) {
    const float* vid0 = (const float*)d_in[0];
    const float* vid1 = (const float*)d_in[1];
    float* out = (float*)d_out;
    dim3 grid(9216);
    dim3 block(256);
    hipLaunchKernelGGL(nls_kernel, grid, block, 0, stream, vid0, vid1, out);
}